// Round 2
// baseline (371.731 us; speedup 1.0000x reference)
//
#include <hip/hip_runtime.h>

#define KK 16
#define DD 15          // K-1
#define NPIX (2048*2048)

__global__ __launch_bounds__(256) void gum_kernel(
    const float* __restrict__ z,      // (DD, NPIX)
    const float* __restrict__ vert,   // (KK, DD) row-major
    float* __restrict__ out)          // [0,NPIX) = X as float, [NPIX,2*NPIX) = dmin
{
    // vS[k][0..14] = vertex k, vS[k][15] = ||v_k||^2. 64B rows -> ds_read_b128.
    __shared__ float vS[KK][16];

    const int t = threadIdx.x;
    if (t < KK) {
        float s = 0.0f;
        #pragma unroll
        for (int d = 0; d < DD; ++d) {
            float v = vert[t * DD + d];
            vS[t][d] = v;
            s += v * v;
        }
        vS[t][DD] = s;
    }
    __syncthreads();

    const int gid  = blockIdx.x * blockDim.x + t;  // pixel-group id (4 pixels)
    const size_t base = (size_t)gid * 4;

    // Issue all 15 plane loads up-front: independent, all in flight (MLP=15),
    // progressive vmcnt drain while zz computes. No accumulators live yet.
    float4 zv[DD];
    #pragma unroll
    for (int d = 0; d < DD; ++d)
        zv[d] = *(const float4*)(z + (size_t)d * NPIX + base);

    float zz[4] = {0.f, 0.f, 0.f, 0.f};
    #pragma unroll
    for (int d = 0; d < DD; ++d) {
        const float* zd = (const float*)&zv[d];
        #pragma unroll
        for (int c = 0; c < 4; ++c) zz[c] += zd[c] * zd[c];
    }

    float bestd[4] = {3.0e38f, 3.0e38f, 3.0e38f, 3.0e38f};
    int   bestk[4] = {0, 0, 0, 0};

    #pragma unroll
    for (int k = 0; k < KK; ++k) {
        float vk[16];
        *(float4*)&vk[0]  = *(const float4*)&vS[k][0];   // ds_read_b128 x4
        *(float4*)&vk[4]  = *(const float4*)&vS[k][4];
        *(float4*)&vk[8]  = *(const float4*)&vS[k][8];
        *(float4*)&vk[12] = *(const float4*)&vS[k][12];  // vk[15] = vv_k

        float cr[4] = {0.f, 0.f, 0.f, 0.f};
        #pragma unroll
        for (int d = 0; d < DD; ++d) {
            const float* zd = (const float*)&zv[d];
            #pragma unroll
            for (int c = 0; c < 4; ++c) cr[c] += vk[d] * zd[c];
        }

        const float vvk = vk[15];
        #pragma unroll
        for (int c = 0; c < 4; ++c) {
            // match ref evaluation order: (zz - 2*cross) + vv
            float d2   = (zz[c] - 2.0f * cr[c]) + vvk;
            float dist = sqrtf(fmaxf(d2, 0.0f));
            if (dist < bestd[c]) { bestd[c] = dist; bestk[c] = k; }  // first-min tie-break
        }
    }

    float4 xo, dm;
    xo.x = (float)bestk[0]; xo.y = (float)bestk[1];
    xo.z = (float)bestk[2]; xo.w = (float)bestk[3];
    dm.x = bestd[0]; dm.y = bestd[1]; dm.z = bestd[2]; dm.w = bestd[3];

    *(float4*)(out + base)        = xo;
    *(float4*)(out + NPIX + base) = dm;
}

extern "C" void kernel_launch(void* const* d_in, const int* in_sizes, int n_in,
                              void* d_out, int out_size, void* d_ws, size_t ws_size,
                              hipStream_t stream) {
    const float* z    = (const float*)d_in[0];   // (15, 2048, 2048) fp32
    const float* vert = (const float*)d_in[1];   // (16, 15) fp32
    float* out = (float*)d_out;                  // 2 * NPIX floats

    const int npix    = in_sizes[0] / DD;        // 4194304
    const int threads = 256;
    const int groups  = npix / 4;                // 4 pixels per thread
    const int blocks  = (groups + threads - 1) / threads;  // 4096

    gum_kernel<<<blocks, threads, 0, stream>>>(z, vert, out);
}